// Round 4
// baseline (340.181 us; speedup 1.0000x reference)
//
#include <hip/hip_runtime.h>
#include <stdint.h>

#define GS   512   // graph size N
#define CF   128   // C_IN = C_OUT
#define XROW 640   // GS + CF
#define NB   128   // batch

typedef __attribute__((ext_vector_type(4))) float          f32x4;
typedef __attribute__((ext_vector_type(8))) short          s16x8;
typedef __attribute__((ext_vector_type(4))) unsigned short u16x4;
typedef __attribute__((ext_vector_type(8))) unsigned short u16x8;

__device__ __forceinline__ unsigned short f2bf(float f) {
    unsigned u = __builtin_bit_cast(unsigned, f);
    u = (u + 0x7fffu + ((u >> 16) & 1u)) >> 16;   // RNE
    return (unsigned short)u;
}
__device__ __forceinline__ float bf2f(unsigned short h) {
    unsigned u = ((unsigned)h) << 16;
    return __builtin_bit_cast(float, u);
}
__device__ __forceinline__ void glds16(const void* g, void* l) {
    __builtin_amdgcn_global_load_lds(
        (const __attribute__((address_space(1))) void*)g,
        (__attribute__((address_space(3))) void*)l, 16, 0, 0);
}

// ---------------------------------------------------------------------------
// k0: W (fp32 [c][f]) -> WTst bf16 in fragment-native order:
//     WTst[((ks*4+lk)*128 + f)*8 + j] = bf16(W[ks*32+lk*8+j][f])
// ---------------------------------------------------------------------------
__global__ __launch_bounds__(256) void k0_wt(const float* __restrict__ W,
                                             unsigned short* __restrict__ WTst) {
    const int e = blockIdx.x * 256 + threadIdx.x;   // 0..16383
    const int j = e & 7, f = (e >> 3) & 127, q = e >> 10;   // q = ks*4+lk
    const int c = (q >> 2) * 32 + (q & 3) * 8 + j;
    WTst[e] = f2bf(W[c * CF + f]);
}

// ---------------------------------------------------------------------------
// k12: fused per-64-row block:
//  sweep: read full X row contiguously; deg->dis (LDS+global); A fp32 copy to
//         out; A bf16 to Abf (linear [b][n][k]); feat bf16 -> LDS (swizzled)
//  mfma : fwdT = bf16( dis[m] * (feat[m,:] @ W) ), k3-staging-linear order
//         [b][kt(16)][lk(4)][f(128)][8 m]
// ---------------------------------------------------------------------------
__global__ __launch_bounds__(256) void k12(const float* __restrict__ X,
                                           const unsigned short* __restrict__ WTst,
                                           float* __restrict__ out,
                                           float* __restrict__ dis,
                                           unsigned short* __restrict__ Abf,
                                           unsigned short* __restrict__ fwdT) {
    __shared__ __align__(16) unsigned short sfb[64 * 128];  // 16KB bf16 feat, swizzled
    __shared__ __align__(16) unsigned short swt[16384];     // 32KB W^T frags
    __shared__ __align__(16) float sdis[64];
    const int t = threadIdx.x, l = t & 63, wv = t >> 6;
    const int m0 = blockIdx.x << 6;
    const int b = m0 >> 9, ml0 = m0 & (GS - 1);

    // stage W^T fragments (L2-hot, overlaps the sweep below)
#pragma unroll
    for (int it = 0; it < 8; ++it)
        glds16((const char*)WTst + it * 4096 + wv * 1024 + l * 16,
               (char*)swt + it * 4096 + wv * 1024);

    // sweep: 16 rows per wave, full-row contiguous reads
    for (int p = 0; p < 16; ++p) {
        const int rw = (p << 2) + wv;                 // block-local row 0..63
        const int gr = m0 + rw;                       // global row b*512+n
        const f32x4* rp = (const f32x4*)(X + (size_t)gr * XROW);
        f32x4 v0 = rp[2 * l], v1 = rp[2 * l + 1];     // A cols 8l..8l+7
        f32x4 vf;
        if (l < 32) vf = rp[128 + l];                 // feat cols 4l..4l+3
        f32x4* op = (f32x4*)(out + (size_t)gr * XROW);
        op[2 * l] = v0; op[2 * l + 1] = v1;
        u16x8 o;
        o[0] = f2bf(v0[0]); o[1] = f2bf(v0[1]); o[2] = f2bf(v0[2]); o[3] = f2bf(v0[3]);
        o[4] = f2bf(v1[0]); o[5] = f2bf(v1[1]); o[6] = f2bf(v1[2]); o[7] = f2bf(v1[3]);
        *(u16x8*)((char*)Abf + ((size_t)gr << 10) + (l << 4)) = o;
        if (l < 32) {
            u16x4 fo;
            fo[0] = f2bf(vf[0]); fo[1] = f2bf(vf[1]); fo[2] = f2bf(vf[2]); fo[3] = f2bf(vf[3]);
            int ad = (rw << 8) + (l << 3);            // byte addr in sfb
            ad ^= (rw & 7) << 4;                      // XOR swizzle (16B granule)
            *(u16x4*)((char*)sfb + ad) = fo;
        }
        float s = (v0[0] + v0[1]) + (v0[2] + v0[3]) + (v1[0] + v1[1]) + (v1[2] + v1[3]);
#pragma unroll
        for (int off = 32; off; off >>= 1) s += __shfl_xor(s, off, 64);
        if (l == 0) {
            float d = (s > 0.f) ? (1.f / sqrtf(s)) : 0.f;
            sdis[rw] = d; dis[gr] = d;
        }
    }
    __syncthreads();

    const int wr = wv >> 1, wc = wv & 1, lr = l & 15, lk = l >> 4;
    f32x4 acc[2][4];
#pragma unroll
    for (int i = 0; i < 2; ++i)
#pragma unroll
        for (int j = 0; j < 4; ++j)
#pragma unroll
            for (int r = 0; r < 4; ++r) acc[i][j][r] = 0.f;

#pragma unroll
    for (int ks = 0; ks < 4; ++ks) {
        s16x8 af[2];
#pragma unroll
        for (int i = 0; i < 2; ++i) {
            int row = (wr << 5) + (i << 4) + lr;
            int ad = (row << 8) + (((ks << 2) | lk) << 4);
            ad ^= (row & 7) << 4;
            af[i] = *(const s16x8*)((char*)sfb + ad);
        }
#pragma unroll
        for (int j = 0; j < 4; ++j) {
            int f = (wc << 6) + (j << 4) + lr;
            s16x8 bfr = *(const s16x8*)&swt[((((ks << 2) | lk) << 7) | f) << 3];
#pragma unroll
            for (int i = 0; i < 2; ++i)
                acc[i][j] = __builtin_amdgcn_mfma_f32_16x16x32_bf16(af[i], bfr, acc[i][j], 0, 0, 0);
        }
    }

    // epilogue: scale by dis[m] (from LDS), store to fwdT in k3 order
#pragma unroll
    for (int i = 0; i < 2; ++i) {
        int mr = (wr << 5) + (i << 4) + (lk << 2);
        f32x4 d4 = *(const f32x4*)&sdis[mr];
        int mg = ml0 + mr;
        int ktm = mg >> 5, q3 = (mg >> 3) & 3, jm = mg & 7;
#pragma unroll
        for (int j = 0; j < 4; ++j) {
            int f = (wc << 6) + (j << 4) + lr;
            u16x4 o;
            o[0] = f2bf(d4[0] * acc[i][j][0]);
            o[1] = f2bf(d4[1] * acc[i][j][1]);
            o[2] = f2bf(d4[2] * acc[i][j][2]);
            o[3] = f2bf(d4[3] * acc[i][j][3]);
            *(u16x4*)((char*)fwdT + ((size_t)b << 17) + (((ktm << 2) | q3) << 11)
                      + (f << 4) + (jm << 1)) = o;
        }
    }
}

// ---------------------------------------------------------------------------
// k3: out[b,n,512+f] = relu( dis[n] * (A[n,:] @ featWD[:,f] + featWD[n,f]) )
// block = 64 rows x 128 f; 4 waves each own 16 rows x 128 f.
// A: per-lane direct global->VGPR from LINEAR Abf, prefetched one phase ahead.
// B: double-buffered LDS, BK=64 (2 kt per phase), linear glds16 staging.
// ---------------------------------------------------------------------------
__global__ __launch_bounds__(256) void k3_gcn(const unsigned short* __restrict__ Abf,
                                              const float* __restrict__ dis,
                                              const unsigned short* __restrict__ fwdT,
                                              float* __restrict__ out) {
    __shared__ __align__(16) unsigned short sb[2][8192];    // 16KB per buf
    const int t = threadIdx.x, l = t & 63, wv = t >> 6, lr = l & 15, lk = l >> 4;
    const int b = blockIdx.x >> 3, bm0 = (blockIdx.x & 7) << 6;
    const char* Bt = (const char*)fwdT + ((size_t)b << 17);
    const char* Ab = (const char*)Abf
        + (((size_t)(b * GS + bm0 + (wv << 4) + lr)) << 10) + (lk << 4);

    auto stage = [&](int buf, int ph) {
#pragma unroll
        for (int it = 0; it < 4; ++it)                       // 16KB = 2 kt-tiles
            glds16(Bt + (ph << 14) + it * 4096 + wv * 1024 + l * 16,
                   (char*)sb[buf] + it * 4096 + wv * 1024);
    };

    f32x4 acc[8];
#pragma unroll
    for (int j = 0; j < 8; ++j)
#pragma unroll
        for (int r = 0; r < 4; ++r) acc[j][r] = 0.f;

    stage(0, 0);
    s16x8 a0 = *(const s16x8*)(Ab);
    s16x8 a1 = *(const s16x8*)(Ab + 64);
    int cur = 0;
    for (int ph = 0; ph < 8; ++ph) {
        __syncthreads();                                     // drains staging vmcnt
        if (ph < 7) stage(cur ^ 1, ph + 1);
        s16x8 n0 = a0, n1 = a1;
        if (ph < 7) {
            n0 = *(const s16x8*)(Ab + ((2 * ph + 2) << 6));
            n1 = *(const s16x8*)(Ab + ((2 * ph + 3) << 6));
        }
#pragma unroll
        for (int j = 0; j < 8; ++j) {
            s16x8 bfr = *(const s16x8*)&sb[cur][(lk << 10) + (j << 7) + (lr << 3)];
            acc[j] = __builtin_amdgcn_mfma_f32_16x16x32_bf16(a0, bfr, acc[j], 0, 0, 0);
        }
#pragma unroll
        for (int j = 0; j < 8; ++j) {
            s16x8 bfr = *(const s16x8*)&sb[cur][4096 + (lk << 10) + (j << 7) + (lr << 3)];
            acc[j] = __builtin_amdgcn_mfma_f32_16x16x32_bf16(a1, bfr, acc[j], 0, 0, 0);
        }
        a0 = n0; a1 = n1; cur ^= 1;
    }

    // epilogue: + identity featWD[n,f], * dis[n], relu, store fp32
    const int n0r = bm0 + (wv << 4) + (lk << 2);            // base of 4 rows
    f32x4 d4 = *(const f32x4*)&dis[(b << 9) + n0r];
    const int ktm = n0r >> 5, q3 = (n0r >> 3) & 3, jm = n0r & 7;
#pragma unroll
    for (int j = 0; j < 8; ++j) {
        int f = (j << 4) + lr;
        u16x4 fw = *(const u16x4*)(Bt + (((ktm << 2) | q3) << 11) + (f << 4) + (jm << 1));
        float* ob = out + ((size_t)(b * GS + n0r)) * XROW + GS + f;
#pragma unroll
        for (int r = 0; r < 4; ++r) {
            float v = d4[r] * (acc[j][r] + bf2f(fw[r]));
            ob[(size_t)r * XROW] = v > 0.f ? v : 0.f;
        }
    }
}

extern "C" void kernel_launch(void* const* d_in, const int* in_sizes, int n_in,
                              void* d_out, int out_size, void* d_ws, size_t ws_size,
                              hipStream_t stream) {
    const float* X = (const float*)d_in[0];
    const float* W = (const float*)d_in[1];
    float* out = (float*)d_out;
    // ws layout (bytes):
    float*          dis  = (float*)d_ws;                                  // 262144
    unsigned short* WTst = (unsigned short*)((char*)d_ws + 262144);       // 32768
    unsigned short* fwdT = (unsigned short*)((char*)d_ws + 294912);       // 16 MiB
    unsigned short* Abf  = (unsigned short*)((char*)d_ws + 17072128);     // 64 MiB

    hipLaunchKernelGGL(k0_wt, dim3(64),            dim3(256), 0, stream, W, WTst);
    hipLaunchKernelGGL(k12,   dim3(NB * GS / 64),  dim3(256), 0, stream, X, WTst, out, dis, Abf, fwdT);
    hipLaunchKernelGGL(k3_gcn, dim3(NB * GS / 64), dim3(256), 0, stream, Abf, dis, fwdT, out);
}

// Round 5
// 335.377 us; speedup vs baseline: 1.0143x; 1.0143x over previous
//
#include <hip/hip_runtime.h>
#include <stdint.h>

#define GS   512   // graph size N
#define CF   128   // C_IN = C_OUT
#define XROW 640   // GS + CF
#define NB   128   // batch

typedef __attribute__((ext_vector_type(4))) float          f32x4;
typedef __attribute__((ext_vector_type(2))) float          f32x2;
typedef __attribute__((ext_vector_type(8))) short          s16x8;
typedef __attribute__((ext_vector_type(4))) unsigned short u16x4;
typedef __attribute__((ext_vector_type(8))) unsigned short u16x8;

__device__ __forceinline__ unsigned short f2bf(float f) {
    unsigned u = __builtin_bit_cast(unsigned, f);
    u = (u + 0x7fffu + ((u >> 16) & 1u)) >> 16;   // RNE
    return (unsigned short)u;
}
__device__ __forceinline__ float bf2f(unsigned short h) {
    unsigned u = ((unsigned)h) << 16;
    return __builtin_bit_cast(float, u);
}
__device__ __forceinline__ void glds16(const void* g, void* l) {
    __builtin_amdgcn_global_load_lds(
        (const __attribute__((address_space(1))) void*)g,
        (__attribute__((address_space(3))) void*)l, 16, 0, 0);
}

// ---------------------------------------------------------------------------
// k0: W (fp32 [c][f]) -> WTst bf16 in fragment-native order:
//     WTst[((ks*4+lk)*128 + f)*8 + j] = bf16(W[ks*32+lk*8+j][f])
// ---------------------------------------------------------------------------
__global__ __launch_bounds__(256) void k0_wt(const float* __restrict__ W,
                                             unsigned short* __restrict__ WTst) {
    const int e = blockIdx.x * 256 + threadIdx.x;   // 0..16383
    const int j = e & 7, f = (e >> 3) & 127, q = e >> 10;   // q = ks*4+lk
    const int c = (q >> 2) * 32 + (q & 3) * 8 + j;
    WTst[e] = f2bf(W[c * CF + f]);
}

// ---------------------------------------------------------------------------
// k12: fused per-64-row block.
//  sweep: contiguous full-row X read; A fp32 copy to out; A bf16 to Abf
//         (linear [b][n][k]); feat bf16 -> LDS (swizzled, 4B/lane);
//         deg partials via 2 shfl + LDS matrix (NOT a 6-deep butterfly —
//         keeps loads issuing back-to-back).
//  tail : reduce spart[64][16] -> sdis / dis.
//  mfma : fwdT = bf16( dis[m] * (feat[m,:] @ W) ), W frags read directly
//         from global (L2 broadcast; no 32KB LDS tile -> 4 blocks/CU).
// ---------------------------------------------------------------------------
__global__ __launch_bounds__(256, 4) void k12(const float* __restrict__ X,
                                              const unsigned short* __restrict__ WTst,
                                              float* __restrict__ out,
                                              float* __restrict__ dis,
                                              unsigned short* __restrict__ Abf,
                                              unsigned short* __restrict__ fwdT) {
    __shared__ __align__(16) unsigned short sfb[64 * 128];  // 16KB bf16 feat, swizzled
    __shared__ __align__(16) float spart[64 * 16];          // 4KB deg partials
    __shared__ __align__(16) float sdis[64];
    const int t = threadIdx.x, l = t & 63, wv = t >> 6;
    const int m0 = blockIdx.x << 6;
    const int b = m0 >> 9, ml0 = m0 & (GS - 1);

    for (int p = 0; p < 16; ++p) {
        const int rw = (p << 2) + wv;                 // block-local row 0..63
        const int gr = m0 + rw;                       // global row b*512+n
        const float* row = X + (size_t)gr * XROW;
        const f32x4* rp = (const f32x4*)row;
        f32x4 v0 = rp[2 * l], v1 = rp[2 * l + 1];     // A cols 8l..8l+7
        f32x2 vf = *(const f32x2*)(row + GS + 2 * l); // feat cols 2l,2l+1
        f32x4* op = (f32x4*)(out + (size_t)gr * XROW);
        op[2 * l] = v0; op[2 * l + 1] = v1;
        u16x8 o;
        o[0] = f2bf(v0[0]); o[1] = f2bf(v0[1]); o[2] = f2bf(v0[2]); o[3] = f2bf(v0[3]);
        o[4] = f2bf(v1[0]); o[5] = f2bf(v1[1]); o[6] = f2bf(v1[2]); o[7] = f2bf(v1[3]);
        *(u16x8*)((char*)Abf + ((size_t)gr << 10) + (l << 4)) = o;
        unsigned fo = (unsigned)f2bf(vf[0]) | ((unsigned)f2bf(vf[1]) << 16);
        int ad = (rw << 8) + (l << 2);                // byte addr in sfb
        ad ^= (rw & 7) << 4;                          // XOR swizzle (16B granule)
        *(unsigned*)((char*)sfb + ad) = fo;
        float s = (v0[0] + v0[1]) + (v0[2] + v0[3]) + (v1[0] + v1[1]) + (v1[2] + v1[3]);
        s += __shfl_xor(s, 32);
        s += __shfl_xor(s, 16);
        if (l < 16) spart[(rw << 4) + l] = s;         // partial over {l,l+16,l+32,l+48}
    }
    __syncthreads();

    // tail: deg per row, dis = rsqrt
    {
        const int r = t >> 2, c = t & 3;
        f32x4 pv = *(const f32x4*)&spart[(r << 4) + (c << 2)];
        float s = (pv[0] + pv[1]) + (pv[2] + pv[3]);
        s += __shfl_xor(s, 1);
        s += __shfl_xor(s, 2);
        if (c == 0) {
            float d = (s > 0.f) ? (1.f / sqrtf(s)) : 0.f;
            sdis[r] = d; dis[m0 + r] = d;
        }
    }
    __syncthreads();

    const int wr = wv >> 1, wc = wv & 1, lr = l & 15, lk = l >> 4;
    f32x4 acc[2][4];
#pragma unroll
    for (int i = 0; i < 2; ++i)
#pragma unroll
        for (int j = 0; j < 4; ++j)
#pragma unroll
            for (int r = 0; r < 4; ++r) acc[i][j][r] = 0.f;

#pragma unroll
    for (int ks = 0; ks < 4; ++ks) {
        s16x8 af[2];
#pragma unroll
        for (int i = 0; i < 2; ++i) {
            int row = (wr << 5) + (i << 4) + lr;
            int ad = (row << 8) + (((ks << 2) | lk) << 4);
            ad ^= (row & 7) << 4;
            af[i] = *(const s16x8*)((char*)sfb + ad);
        }
#pragma unroll
        for (int j = 0; j < 4; ++j) {
            int f = (wc << 6) + (j << 4) + lr;
            s16x8 bfr = *(const s16x8*)(WTst + (((((ks << 2) | lk) << 7) | f) << 3));
#pragma unroll
            for (int i = 0; i < 2; ++i)
                acc[i][j] = __builtin_amdgcn_mfma_f32_16x16x32_bf16(af[i], bfr, acc[i][j], 0, 0, 0);
        }
    }

    // epilogue: scale by dis[m] (LDS), store to fwdT in k3 order
#pragma unroll
    for (int i = 0; i < 2; ++i) {
        int mr = (wr << 5) + (i << 4) + (lk << 2);
        f32x4 d4 = *(const f32x4*)&sdis[mr];
        int mg = ml0 + mr;
        int ktm = mg >> 5, q3 = (mg >> 3) & 3, jm = mg & 7;
#pragma unroll
        for (int j = 0; j < 4; ++j) {
            int f = (wc << 6) + (j << 4) + lr;
            u16x4 o;
            o[0] = f2bf(d4[0] * acc[i][j][0]);
            o[1] = f2bf(d4[1] * acc[i][j][1]);
            o[2] = f2bf(d4[2] * acc[i][j][2]);
            o[3] = f2bf(d4[3] * acc[i][j][3]);
            *(u16x4*)((char*)fwdT + ((size_t)b << 17) + (((ktm << 2) | q3) << 11)
                      + (f << 4) + (jm << 1)) = o;
        }
    }
}

// ---------------------------------------------------------------------------
// k3: out[b,n,512+f] = relu( dis[n] * (A[n,:] @ featWD[:,f] + featWD[n,f]) )
// XCD-swizzled blockIdx: the 8 blocks sharing batch b land on ONE XCD so the
// per-batch 128KB fwdT staging hits that XCD's L2 instead of L3/HBM 8x.
// A: per-lane direct global->VGPR from LINEAR Abf, prefetched one phase ahead.
// B: double-buffered LDS, BK=64 (2 kt per phase), linear glds16 staging.
// ---------------------------------------------------------------------------
__global__ __launch_bounds__(256) void k3_gcn(const unsigned short* __restrict__ Abf,
                                              const float* __restrict__ dis,
                                              const unsigned short* __restrict__ fwdT,
                                              float* __restrict__ out) {
    __shared__ __align__(16) unsigned short sb[2][8192];    // 16KB per buf
    const int t = threadIdx.x, l = t & 63, wv = t >> 6, lr = l & 15, lk = l >> 4;
    const int ord = blockIdx.x;
    const int L = ((ord & 7) << 7) + (ord >> 3);            // XCD-chunked, bijective
    const int b = L >> 3, bm0 = (L & 7) << 6;
    const char* Bt = (const char*)fwdT + ((size_t)b << 17);
    const char* Ab = (const char*)Abf
        + (((size_t)(b * GS + bm0 + (wv << 4) + lr)) << 10) + (lk << 4);

    auto stage = [&](int buf, int ph) {
#pragma unroll
        for (int it = 0; it < 4; ++it)                       // 16KB = 2 kt-tiles
            glds16(Bt + (ph << 14) + it * 4096 + wv * 1024 + l * 16,
                   (char*)sb[buf] + it * 4096 + wv * 1024);
    };

    f32x4 acc[8];
#pragma unroll
    for (int j = 0; j < 8; ++j)
#pragma unroll
        for (int r = 0; r < 4; ++r) acc[j][r] = 0.f;

    stage(0, 0);
    s16x8 a0 = *(const s16x8*)(Ab);
    s16x8 a1 = *(const s16x8*)(Ab + 64);
    int cur = 0;
    for (int ph = 0; ph < 8; ++ph) {
        __syncthreads();                                     // drains staging vmcnt
        if (ph < 7) stage(cur ^ 1, ph + 1);
        s16x8 n0 = a0, n1 = a1;
        if (ph < 7) {
            n0 = *(const s16x8*)(Ab + ((2 * ph + 2) << 6));
            n1 = *(const s16x8*)(Ab + ((2 * ph + 3) << 6));
        }
#pragma unroll
        for (int j = 0; j < 8; ++j) {
            s16x8 bfr = *(const s16x8*)&sb[cur][(lk << 10) + (j << 7) + (lr << 3)];
            acc[j] = __builtin_amdgcn_mfma_f32_16x16x32_bf16(a0, bfr, acc[j], 0, 0, 0);
        }
#pragma unroll
        for (int j = 0; j < 8; ++j) {
            s16x8 bfr = *(const s16x8*)&sb[cur][4096 + (lk << 10) + (j << 7) + (lr << 3)];
            acc[j] = __builtin_amdgcn_mfma_f32_16x16x32_bf16(a1, bfr, acc[j], 0, 0, 0);
        }
        a0 = n0; a1 = n1; cur ^= 1;
    }

    // epilogue: + identity featWD[n,f], * dis[n], relu, store fp32
    const int n0r = bm0 + (wv << 4) + (lk << 2);            // base of 4 rows
    f32x4 d4 = *(const f32x4*)&dis[(b << 9) + n0r];
    const int ktm = n0r >> 5, q3 = (n0r >> 3) & 3, jm = n0r & 7;
#pragma unroll
    for (int j = 0; j < 8; ++j) {
        int f = (j << 4) + lr;
        u16x4 fw = *(const u16x4*)(Bt + (((ktm << 2) | q3) << 11) + (f << 4) + (jm << 1));
        float* ob = out + ((size_t)(b * GS + n0r)) * XROW + GS + f;
#pragma unroll
        for (int r = 0; r < 4; ++r) {
            float v = d4[r] * (acc[j][r] + bf2f(fw[r]));
            ob[(size_t)r * XROW] = v > 0.f ? v : 0.f;
        }
    }
}

extern "C" void kernel_launch(void* const* d_in, const int* in_sizes, int n_in,
                              void* d_out, int out_size, void* d_ws, size_t ws_size,
                              hipStream_t stream) {
    const float* X = (const float*)d_in[0];
    const float* W = (const float*)d_in[1];
    float* out = (float*)d_out;
    // ws layout (bytes):
    float*          dis  = (float*)d_ws;                                  // 262144
    unsigned short* WTst = (unsigned short*)((char*)d_ws + 262144);       // 32768
    unsigned short* fwdT = (unsigned short*)((char*)d_ws + 294912);       // 16 MiB
    unsigned short* Abf  = (unsigned short*)((char*)d_ws + 17072128);     // 64 MiB

    hipLaunchKernelGGL(k0_wt, dim3(64),            dim3(256), 0, stream, W, WTst);
    hipLaunchKernelGGL(k12,   dim3(NB * GS / 64),  dim3(256), 0, stream, X, WTst, out, dis, Abf, fwdT);
    hipLaunchKernelGGL(k3_gcn, dim3(NB * GS / 64), dim3(256), 0, stream, Abf, dis, fwdT, out);
}